// Round 4
// baseline (248.647 us; speedup 1.0000x reference)
//
#include <hip/hip_runtime.h>
#include <hip/hip_bf16.h>
#include <hip/hip_fp16.h>
#include <math.h>

#define B_ 8
#define N_ 2048
#define F_ 128

typedef __attribute__((ext_vector_type(8))) _Float16 half8;
typedef __attribute__((ext_vector_type(4))) float f32x4;

// ---------------------------------------------------------------------------
// Kernel 1 (fused): blocks [0,512): Wh = h@W^T -> fp16 B-frag swizzled WhH,
// plus exact fp32 sv/tv.  Blocks [512,4608): pack adj!=0 into bitmask
// (4 MB, bit j of row r at mask[r*32 + j/64] bit j%64) -- pure-BW streaming
// read of adj overlapped with the GEMM blocks.
// ---------------------------------------------------------------------------
__global__ __launch_bounds__(256) void k_prep(
    const float* __restrict__ h, const float* __restrict__ W,
    const float* __restrict__ a, const int* __restrict__ adj,
    _Float16* __restrict__ WhH, float* __restrict__ sv, float* __restrict__ tv,
    unsigned long long* __restrict__ mask)
{
    __shared__ float h_s[64][129];
    __shared__ float Wt[128][68];
    __shared__ float wsm[128], wtm[128];
    __shared__ float sred[64][4], tred[64][4];

    const int t = threadIdx.x;

    if (blockIdx.x >= 512) {
        // ---- adj -> bitmask pack: 4096 blocks x 4 waves = 16384 rows ----
        const int wv = t >> 6, lane = t & 63;
        const int row = (blockIdx.x - 512) * 4 + wv;
        const int* ap = adj + ((size_t)row << 11);
        unsigned long long* mp = mask + (size_t)row * 32;
        #pragma unroll
        for (int it0 = 0; it0 < 32; it0 += 8) {
            int v[8];
            #pragma unroll
            for (int u = 0; u < 8; ++u) v[u] = ap[(it0 + u) * 64 + lane];
            #pragma unroll
            for (int u = 0; u < 8; ++u) {
                unsigned long long bm = __ballot(v[u] != 0);
                if (lane == 0) mp[it0 + u] = bm;
            }
        }
        return;
    }

    const int rowblk = blockIdx.x >> 1;
    const int ohalf  = blockIdx.x & 1;
    const int r0 = rowblk * 64;

    {
        const int f = (t & 31) * 4;
        #pragma unroll
        for (int it = 0; it < 8; ++it) {
            const int r = (t >> 5) + it * 8;
            float4 v = *(const float4*)&h[(size_t)(r0 + r) * F_ + f];
            h_s[r][f] = v.x; h_s[r][f + 1] = v.y;
            h_s[r][f + 2] = v.z; h_s[r][f + 3] = v.w;
        }
    }
    {
        const int f = (t & 31) * 4;
        #pragma unroll
        for (int it = 0; it < 8; ++it) {
            const int o = (t >> 5) + it * 8;
            float4 v = *(const float4*)&W[(size_t)(ohalf * 64 + o) * F_ + f];
            Wt[f][o] = v.x; Wt[f + 1][o] = v.y;
            Wt[f + 2][o] = v.z; Wt[f + 3][o] = v.w;
        }
    }
    {
        const int f = t & 127;
        const int which = t >> 7;
        const float* av = a + which * 128;
        float acc = 0.f;
        for (int o = 0; o < 128; ++o)
            acc += W[(size_t)o * F_ + f] * av[o];
        if (which == 0) wsm[f] = acc; else wtm[f] = acc;
    }
    __syncthreads();

    const int o4 = t & 15;
    const int r4 = t >> 4;
    float acc[4][4];
    #pragma unroll
    for (int i = 0; i < 4; ++i)
        #pragma unroll
        for (int j = 0; j < 4; ++j) acc[i][j] = 0.f;

    #pragma unroll 4
    for (int k = 0; k < 128; ++k) {
        float4 w = *(const float4*)&Wt[k][o4 * 4];
        float h0 = h_s[r4 * 4 + 0][k];
        float h1 = h_s[r4 * 4 + 1][k];
        float h2 = h_s[r4 * 4 + 2][k];
        float h3 = h_s[r4 * 4 + 3][k];
        acc[0][0] += h0 * w.x; acc[0][1] += h0 * w.y; acc[0][2] += h0 * w.z; acc[0][3] += h0 * w.w;
        acc[1][0] += h1 * w.x; acc[1][1] += h1 * w.y; acc[1][2] += h1 * w.z; acc[1][3] += h1 * w.w;
        acc[2][0] += h2 * w.x; acc[2][1] += h2 * w.y; acc[2][2] += h2 * w.z; acc[2][3] += h2 * w.w;
        acc[3][0] += h3 * w.x; acc[3][1] += h3 * w.y; acc[3][2] += h3 * w.z; acc[3][3] += h3 * w.w;
    }

    {
        const int Rbase = r0 + r4 * 4;
        const int b    = Rbase >> 11;
        const int jj   = Rbase & 2047;
        const int jblk = jj >> 5;
        const int k8   = (jj >> 3) & 3;
        const int kk   = jj & 7;
        #pragma unroll
        for (int jo = 0; jo < 4; ++jo) {
            const int o = ohalf * 64 + o4 * 4 + jo;
            size_t off = ((size_t)(b * 64 + jblk) * 128 + o) * 32 + k8 * 8 + kk;
            union { _Float16 x[4]; uint2 u; } pk;
            pk.x[0] = (_Float16)acc[0][jo];
            pk.x[1] = (_Float16)acc[1][jo];
            pk.x[2] = (_Float16)acc[2][jo];
            pk.x[3] = (_Float16)acc[3][jo];
            *(uint2*)(WhH + off) = pk.u;
        }
    }

    {
        const int r = t & 63, part = t >> 6;
        float as_ = 0.f, at_ = 0.f;
        const int kb = part * 32;
        for (int k = kb; k < kb + 32; ++k) {
            float hv = h_s[r][k];
            as_ += hv * wsm[k];
            at_ += hv * wtm[k];
        }
        sred[r][part] = as_; tred[r][part] = at_;
    }
    __syncthreads();
    if (ohalf == 0 && t < 64) {
        sv[r0 + t] = sred[t][0] + sred[t][1] + sred[t][2] + sred[t][3];
        tv[r0 + t] = tred[t][0] + tred[t][1] + tred[t][2] + tred[t][3];
    }
}

// ---------------------------------------------------------------------------
// Kernel 2: flash-GAT with bitmask adjacency, 32 i-rows per wave.
// 512 blocks x 256 threads; block = (b, 32-row i-tile); wave wv owns
// j in [wv*512, +512), 16 chunks of 32.  Two A-fragments per wave (rows
// m_ and m_+16) share every B-fragment load -> 16 MFMA per 8 dwordx4.
// End: 4-wave partial-O/l reduce via 64KB LDS (2 blocks/CU).
// ---------------------------------------------------------------------------
__global__ __launch_bounds__(256, 2) void k_attn(
    const _Float16* __restrict__ WhH, const float* __restrict__ sv,
    const float* __restrict__ tv, const unsigned int* __restrict__ maskd,
    float* __restrict__ out)
{
    __shared__ float redO[4][32][128];   // 64 KB
    __shared__ float redL[4][32];
    __shared__ float tmr[4];

    const int t  = threadIdx.x;
    const int b  = blockIdx.x >> 6;
    const int i0 = (blockIdx.x & 63) * 32;
    const float* tb = tv + ((size_t)b << 11);

    // per-batch tmax (8 KB, L2-hot)
    float tm = -INFINITY;
    #pragma unroll
    for (int k = 0; k < 8; ++k) tm = fmaxf(tm, tb[t + k * 256]);
    #pragma unroll
    for (int k = 32; k; k >>= 1) tm = fmaxf(tm, __shfl_xor(tm, k, 64));
    if ((t & 63) == 0) tmr[t >> 6] = tm;
    __syncthreads();
    const float tmax = fmaxf(fmaxf(tmr[0], tmr[1]), fmaxf(tmr[2], tmr[3]));

    const int wv   = t >> 6;
    const int lane = t & 63;
    const int m_   = lane & 15;
    const int q_   = lane >> 4;

    const float s0 = sv[((size_t)b << 11) + i0 + m_];
    const float s1 = sv[((size_t)b << 11) + i0 + 16 + m_];
    const float M0 = fmaxf(s0 + tmax, 0.f);   // upper bound on leaky(s0+t_j)
    const float M1 = fmaxf(s1 + tmax, 0.f);

    const unsigned int* mrow0 =
        maskd + (size_t)(((b << 11) + i0 + m_)) * 64 + wv * 16;
    const unsigned int* mrow1 = mrow0 + 16 * 64;
    const float* tq = tb + wv * 512 + q_ * 8;
    const _Float16* wbase = WhH + (((size_t)b * 64 + wv * 16) << 12)
                          + (size_t)m_ * 32 + q_ * 8;

    f32x4 acc0[8], acc1[8];
    #pragma unroll
    for (int n = 0; n < 8; ++n) {
        acc0[n] = (f32x4){0.f, 0.f, 0.f, 0.f};
        acc1[n] = (f32x4){0.f, 0.f, 0.f, 0.f};
    }
    float lsum0 = 0.f, lsum1 = 0.f;

    unsigned int mc0 = mrow0[0], mc1 = mrow1[0];

    for (int jj = 0; jj < 16; ++jj) {
        const int nxt = (jj + 1) & 15;               // wrap: harmless
        unsigned int mn0 = mrow0[nxt];
        unsigned int mn1 = mrow1[nxt];

        // B fragments first (overlap their latency with the exp block)
        const _Float16* wb = wbase + ((size_t)jj << 12);
        half8 bf[8];
        #pragma unroll
        for (int n = 0; n < 8; ++n)
            bf[n] = *(const half8*)(wb + n * 512);

        float4 tL = *(const float4*)&tq[jj * 32];
        float4 tH = *(const float4*)&tq[jj * 32 + 4];
        const unsigned int bq0 = mc0 >> (q_ * 8);
        const unsigned int bq1 = mc1 >> (q_ * 8);

        float tvk[8] = {tL.x, tL.y, tL.z, tL.w, tH.x, tH.y, tH.z, tH.w};
        half8 af0, af1;
        #pragma unroll
        for (int k = 0; k < 8; ++k) {
            float e0 = s0 + tvk[k]; e0 = fmaxf(e0, 0.2f * e0);
            float p0 = (bq0 >> k) & 1 ? __expf(e0 - M0) : 0.f;
            float e1 = s1 + tvk[k]; e1 = fmaxf(e1, 0.2f * e1);
            float p1 = (bq1 >> k) & 1 ? __expf(e1 - M1) : 0.f;
            lsum0 += p0; lsum1 += p1;
            af0[k] = (_Float16)p0; af1[k] = (_Float16)p1;
        }

        #pragma unroll
        for (int n = 0; n < 8; ++n) {
            acc0[n] = __builtin_amdgcn_mfma_f32_16x16x32_f16(af0, bf[n], acc0[n], 0, 0, 0);
            acc1[n] = __builtin_amdgcn_mfma_f32_16x16x32_f16(af1, bf[n], acc1[n], 0, 0, 0);
        }
        mc0 = mn0; mc1 = mn1;
    }

    // l partial reduce over q-lanes (bits 4,5)
    lsum0 += __shfl_xor(lsum0, 16, 64); lsum0 += __shfl_xor(lsum0, 32, 64);
    lsum1 += __shfl_xor(lsum1, 16, 64); lsum1 += __shfl_xor(lsum1, 32, 64);
    if (q_ == 0) { redL[wv][m_] = lsum0; redL[wv][16 + m_] = lsum1; }

    // dump partial O (C/D layout: row = q_*4+r, col = n*16+m_)
    #pragma unroll
    for (int n = 0; n < 8; ++n)
        #pragma unroll
        for (int r = 0; r < 4; ++r) {
            redO[wv][q_ * 4 + r][n * 16 + m_]      = acc0[n][r];
            redO[wv][16 + q_ * 4 + r][n * 16 + m_] = acc1[n][r];
        }
    __syncthreads();

    // combine 4 waves: thread t -> row t>>3, cols (t&7)*16..+16
    {
        const int row = t >> 3;
        const int c0  = (t & 7) * 16;
        const float li = redL[0][row] + redL[1][row] + redL[2][row] + redL[3][row];
        const float sc = li > 0.f ? 1.f / li : 0.f;   // empty row -> 0
        float* op = out + (((size_t)((b << 11) + i0 + row)) << 7) + c0;
        #pragma unroll
        for (int c = 0; c < 16; ++c) {
            float v = redO[0][row][c0 + c] + redO[1][row][c0 + c]
                    + redO[2][row][c0 + c] + redO[3][row][c0 + c];
            op[c] = v * sc;
        }
    }
}

extern "C" void kernel_launch(void* const* d_in, const int* in_sizes, int n_in,
                              void* d_out, int out_size, void* d_ws, size_t ws_size,
                              hipStream_t stream) {
    const float* h   = (const float*)d_in[0];
    const int*   adj = (const int*)d_in[1];
    const float* W   = (const float*)d_in[2];
    const float* a   = (const float*)d_in[3];
    float* out = (float*)d_out;

    _Float16* WhH = (_Float16*)d_ws;                               // 4 MB
    float* sv = (float*)((char*)d_ws + (size_t)4 * 1024 * 1024);   // 64 KB
    float* tv = sv + (size_t)B_ * N_;                              // 64 KB
    unsigned long long* mask =
        (unsigned long long*)((char*)d_ws + (size_t)4 * 1024 * 1024 + 256 * 1024);

    k_prep<<<4608, 256, 0, stream>>>(h, W, a, adj, WhH, sv, tv, mask);
    k_attn<<<512, 256, 0, stream>>>(WhH, sv, tv, (const unsigned int*)mask, out);
}

// Round 5
// 248.031 us; speedup vs baseline: 1.0025x; 1.0025x over previous
//
#include <hip/hip_runtime.h>
#include <hip/hip_bf16.h>
#include <hip/hip_fp16.h>
#include <math.h>

#define B_ 8
#define N_ 2048
#define F_ 128

typedef __attribute__((ext_vector_type(8))) _Float16 half8;
typedef __attribute__((ext_vector_type(4))) float f32x4;

// ---------------------------------------------------------------------------
// Kernel 0: pack adj!=0 into bitmask. 4096 blocks x 256 (4 waves = 4 rows).
// Zero LDS, tiny VGPR -> full occupancy, pure HBM stream (128 MB read).
// mask[row*32 + j/64] bit (j%64).
// ---------------------------------------------------------------------------
__global__ __launch_bounds__(256) void k_mask(
    const int* __restrict__ adj, unsigned long long* __restrict__ mask)
{
    const int wv = threadIdx.x >> 6, lane = threadIdx.x & 63;
    const int row = blockIdx.x * 4 + wv;
    const int* ap = adj + ((size_t)row << 11);
    unsigned long long* mp = mask + (size_t)row * 32;
    #pragma unroll
    for (int it0 = 0; it0 < 32; it0 += 8) {
        int v[8];
        #pragma unroll
        for (int u = 0; u < 8; ++u) v[u] = ap[(it0 + u) * 64 + lane];
        #pragma unroll
        for (int u = 0; u < 8; ++u) {
            unsigned long long bm = __ballot(v[u] != 0);
            if (lane == 0) mp[it0 + u] = bm;
        }
    }
}

// ---------------------------------------------------------------------------
// Kernel 1: Wh = h @ W^T (fp32), fp16 B-frag swizzled out; exact fp32 sv/tv.
// ---------------------------------------------------------------------------
__global__ __launch_bounds__(256) void k_gemm(
    const float* __restrict__ h, const float* __restrict__ W,
    const float* __restrict__ a,
    _Float16* __restrict__ WhH, float* __restrict__ sv, float* __restrict__ tv)
{
    __shared__ float h_s[64][129];
    __shared__ float Wt[128][68];
    __shared__ float wsm[128], wtm[128];
    __shared__ float sred[64][4], tred[64][4];

    const int t = threadIdx.x;
    const int rowblk = blockIdx.x >> 1;
    const int ohalf  = blockIdx.x & 1;
    const int r0 = rowblk * 64;

    {
        const int f = (t & 31) * 4;
        #pragma unroll
        for (int it = 0; it < 8; ++it) {
            const int r = (t >> 5) + it * 8;
            float4 v = *(const float4*)&h[(size_t)(r0 + r) * F_ + f];
            h_s[r][f] = v.x; h_s[r][f + 1] = v.y;
            h_s[r][f + 2] = v.z; h_s[r][f + 3] = v.w;
        }
    }
    {
        const int f = (t & 31) * 4;
        #pragma unroll
        for (int it = 0; it < 8; ++it) {
            const int o = (t >> 5) + it * 8;
            float4 v = *(const float4*)&W[(size_t)(ohalf * 64 + o) * F_ + f];
            Wt[f][o] = v.x; Wt[f + 1][o] = v.y;
            Wt[f + 2][o] = v.z; Wt[f + 3][o] = v.w;
        }
    }
    {
        const int f = t & 127;
        const int which = t >> 7;
        const float* av = a + which * 128;
        float acc = 0.f;
        for (int o = 0; o < 128; ++o)
            acc += W[(size_t)o * F_ + f] * av[o];
        if (which == 0) wsm[f] = acc; else wtm[f] = acc;
    }
    __syncthreads();

    const int o4 = t & 15;
    const int r4 = t >> 4;
    float acc[4][4];
    #pragma unroll
    for (int i = 0; i < 4; ++i)
        #pragma unroll
        for (int j = 0; j < 4; ++j) acc[i][j] = 0.f;

    #pragma unroll 4
    for (int k = 0; k < 128; ++k) {
        float4 w = *(const float4*)&Wt[k][o4 * 4];
        float h0 = h_s[r4 * 4 + 0][k];
        float h1 = h_s[r4 * 4 + 1][k];
        float h2 = h_s[r4 * 4 + 2][k];
        float h3 = h_s[r4 * 4 + 3][k];
        acc[0][0] += h0 * w.x; acc[0][1] += h0 * w.y; acc[0][2] += h0 * w.z; acc[0][3] += h0 * w.w;
        acc[1][0] += h1 * w.x; acc[1][1] += h1 * w.y; acc[1][2] += h1 * w.z; acc[1][3] += h1 * w.w;
        acc[2][0] += h2 * w.x; acc[2][1] += h2 * w.y; acc[2][2] += h2 * w.z; acc[2][3] += h2 * w.w;
        acc[3][0] += h3 * w.x; acc[3][1] += h3 * w.y; acc[3][2] += h3 * w.z; acc[3][3] += h3 * w.w;
    }

    {
        const int Rbase = r0 + r4 * 4;
        const int b    = Rbase >> 11;
        const int jj   = Rbase & 2047;
        const int jblk = jj >> 5;
        const int k8   = (jj >> 3) & 3;
        const int kk   = jj & 7;
        #pragma unroll
        for (int jo = 0; jo < 4; ++jo) {
            const int o = ohalf * 64 + o4 * 4 + jo;
            size_t off = ((size_t)(b * 64 + jblk) * 128 + o) * 32 + k8 * 8 + kk;
            union { _Float16 x[4]; uint2 u; } pk;
            pk.x[0] = (_Float16)acc[0][jo];
            pk.x[1] = (_Float16)acc[1][jo];
            pk.x[2] = (_Float16)acc[2][jo];
            pk.x[3] = (_Float16)acc[3][jo];
            *(uint2*)(WhH + off) = pk.u;
        }
    }

    {
        const int r = t & 63, part = t >> 6;
        float as_ = 0.f, at_ = 0.f;
        const int kb = part * 32;
        for (int k = kb; k < kb + 32; ++k) {
            float hv = h_s[r][k];
            as_ += hv * wsm[k];
            at_ += hv * wtm[k];
        }
        sred[r][part] = as_; tred[r][part] = at_;
    }
    __syncthreads();
    if (ohalf == 0 && t < 64) {
        sv[r0 + t] = sred[t][0] + sred[t][1] + sred[t][2] + sred[t][3];
        tv[r0 + t] = tred[t][0] + tred[t][1] + tred[t][2] + tred[t][3];
    }
}

// ---------------------------------------------------------------------------
// Kernel 2: flash-GAT, bitmask adjacency, 32 i-rows/block, XCD-swizzled:
// b = blockIdx & 7 -> all 64 blocks of batch b on one XCD (blockIdx%8 rr),
// per-XCD L2 working set ~1 MB (WhH slice + mask slice + s/t) -> L2-hot.
// ---------------------------------------------------------------------------
__global__ __launch_bounds__(256, 2) void k_attn(
    const _Float16* __restrict__ WhH, const float* __restrict__ sv,
    const float* __restrict__ tv, const unsigned int* __restrict__ maskd,
    float* __restrict__ out)
{
    __shared__ float redO[4][32][128];   // 64 KB
    __shared__ float redL[4][32];
    __shared__ float tmr[4];

    const int t  = threadIdx.x;
    const int b  = blockIdx.x & 7;         // XCD id (speed heuristic only)
    const int i0 = (blockIdx.x >> 3) * 32;
    const float* tb = tv + ((size_t)b << 11);

    float tm = -INFINITY;
    #pragma unroll
    for (int k = 0; k < 8; ++k) tm = fmaxf(tm, tb[t + k * 256]);
    #pragma unroll
    for (int k = 32; k; k >>= 1) tm = fmaxf(tm, __shfl_xor(tm, k, 64));
    if ((t & 63) == 0) tmr[t >> 6] = tm;
    __syncthreads();
    const float tmax = fmaxf(fmaxf(tmr[0], tmr[1]), fmaxf(tmr[2], tmr[3]));

    const int wv   = t >> 6;
    const int lane = t & 63;
    const int m_   = lane & 15;
    const int q_   = lane >> 4;

    const float s0 = sv[((size_t)b << 11) + i0 + m_];
    const float s1 = sv[((size_t)b << 11) + i0 + 16 + m_];
    const float M0 = fmaxf(s0 + tmax, 0.f);
    const float M1 = fmaxf(s1 + tmax, 0.f);

    const unsigned int* mrow0 =
        maskd + (size_t)(((b << 11) + i0 + m_)) * 64 + wv * 16;
    const unsigned int* mrow1 = mrow0 + 16 * 64;
    const float* tq = tb + wv * 512 + q_ * 8;
    const _Float16* wbase = WhH + (((size_t)b * 64 + wv * 16) << 12)
                          + (size_t)m_ * 32 + q_ * 8;

    f32x4 acc0[8], acc1[8];
    #pragma unroll
    for (int n = 0; n < 8; ++n) {
        acc0[n] = (f32x4){0.f, 0.f, 0.f, 0.f};
        acc1[n] = (f32x4){0.f, 0.f, 0.f, 0.f};
    }
    float lsum0 = 0.f, lsum1 = 0.f;

    unsigned int mc0 = mrow0[0], mc1 = mrow1[0];

    for (int jj = 0; jj < 16; ++jj) {
        const int nxt = (jj + 1) & 15;               // wrap: harmless
        unsigned int mn0 = mrow0[nxt];
        unsigned int mn1 = mrow1[nxt];

        const _Float16* wb = wbase + ((size_t)jj << 12);
        half8 bf[8];
        #pragma unroll
        for (int n = 0; n < 8; ++n)
            bf[n] = *(const half8*)(wb + n * 512);

        float4 tL = *(const float4*)&tq[jj * 32];
        float4 tH = *(const float4*)&tq[jj * 32 + 4];
        const unsigned int bq0 = mc0 >> (q_ * 8);
        const unsigned int bq1 = mc1 >> (q_ * 8);

        float tvk[8] = {tL.x, tL.y, tL.z, tL.w, tH.x, tH.y, tH.z, tH.w};
        half8 af0, af1;
        #pragma unroll
        for (int k = 0; k < 8; ++k) {
            float e0 = s0 + tvk[k]; e0 = fmaxf(e0, 0.2f * e0);
            float p0 = (bq0 >> k) & 1 ? __expf(e0 - M0) : 0.f;
            float e1 = s1 + tvk[k]; e1 = fmaxf(e1, 0.2f * e1);
            float p1 = (bq1 >> k) & 1 ? __expf(e1 - M1) : 0.f;
            lsum0 += p0; lsum1 += p1;
            af0[k] = (_Float16)p0; af1[k] = (_Float16)p1;
        }

        #pragma unroll
        for (int n = 0; n < 8; ++n) {
            acc0[n] = __builtin_amdgcn_mfma_f32_16x16x32_f16(af0, bf[n], acc0[n], 0, 0, 0);
            acc1[n] = __builtin_amdgcn_mfma_f32_16x16x32_f16(af1, bf[n], acc1[n], 0, 0, 0);
        }
        mc0 = mn0; mc1 = mn1;
    }

    lsum0 += __shfl_xor(lsum0, 16, 64); lsum0 += __shfl_xor(lsum0, 32, 64);
    lsum1 += __shfl_xor(lsum1, 16, 64); lsum1 += __shfl_xor(lsum1, 32, 64);
    if (q_ == 0) { redL[wv][m_] = lsum0; redL[wv][16 + m_] = lsum1; }

    #pragma unroll
    for (int n = 0; n < 8; ++n)
        #pragma unroll
        for (int r = 0; r < 4; ++r) {
            redO[wv][q_ * 4 + r][n * 16 + m_]      = acc0[n][r];
            redO[wv][16 + q_ * 4 + r][n * 16 + m_] = acc1[n][r];
        }
    __syncthreads();

    {
        const int row = t >> 3;
        const int c0  = (t & 7) * 16;
        const float li = redL[0][row] + redL[1][row] + redL[2][row] + redL[3][row];
        const float sc = li > 0.f ? 1.f / li : 0.f;
        float* op = out + (((size_t)((b << 11) + i0 + row)) << 7) + c0;
        #pragma unroll
        for (int c = 0; c < 16; ++c) {
            float v = redO[0][row][c0 + c] + redO[1][row][c0 + c]
                    + redO[2][row][c0 + c] + redO[3][row][c0 + c];
            op[c] = v * sc;
        }
    }
}

extern "C" void kernel_launch(void* const* d_in, const int* in_sizes, int n_in,
                              void* d_out, int out_size, void* d_ws, size_t ws_size,
                              hipStream_t stream) {
    const float* h   = (const float*)d_in[0];
    const int*   adj = (const int*)d_in[1];
    const float* W   = (const float*)d_in[2];
    const float* a   = (const float*)d_in[3];
    float* out = (float*)d_out;

    _Float16* WhH = (_Float16*)d_ws;                               // 4 MB
    float* sv = (float*)((char*)d_ws + (size_t)4 * 1024 * 1024);   // 64 KB
    float* tv = sv + (size_t)B_ * N_;                              // 64 KB
    unsigned long long* mask =
        (unsigned long long*)((char*)d_ws + (size_t)4 * 1024 * 1024 + 256 * 1024);

    k_mask<<<4096, 256, 0, stream>>>(adj, mask);
    k_gemm<<<512, 256, 0, stream>>>(h, W, a, WhH, sv, tv);
    k_attn<<<512, 256, 0, stream>>>(WhH, sv, tv, (const unsigned int*)mask, out);
}

// Round 6
// 235.082 us; speedup vs baseline: 1.0577x; 1.0551x over previous
//
#include <hip/hip_runtime.h>
#include <hip/hip_bf16.h>
#include <hip/hip_fp16.h>
#include <math.h>

#define B_ 8
#define N_ 2048
#define F_ 128

typedef __attribute__((ext_vector_type(8))) _Float16 half8;
typedef __attribute__((ext_vector_type(4))) float f32x4;

// ---------------------------------------------------------------------------
// Kernel 1: Wh = h @ W^T (fp32), fp16 B-frag swizzled out; exact fp32 sv/tv.
// WhH layout: element (b, j, o) at ((b*64 + j/32)*128 + o)*32 + ((j/8)%4)*8
// + (j%8)  -> each 32-j chunk is one contiguous 8 KB block.
// ---------------------------------------------------------------------------
__global__ __launch_bounds__(256) void k_gemm(
    const float* __restrict__ h, const float* __restrict__ W,
    const float* __restrict__ a,
    _Float16* __restrict__ WhH, float* __restrict__ sv, float* __restrict__ tv)
{
    __shared__ float h_s[64][129];
    __shared__ float Wt[128][68];
    __shared__ float wsm[128], wtm[128];
    __shared__ float sred[64][4], tred[64][4];

    const int t = threadIdx.x;
    const int rowblk = blockIdx.x >> 1;
    const int ohalf  = blockIdx.x & 1;
    const int r0 = rowblk * 64;

    {
        const int f = (t & 31) * 4;
        #pragma unroll
        for (int it = 0; it < 8; ++it) {
            const int r = (t >> 5) + it * 8;
            float4 v = *(const float4*)&h[(size_t)(r0 + r) * F_ + f];
            h_s[r][f] = v.x; h_s[r][f + 1] = v.y;
            h_s[r][f + 2] = v.z; h_s[r][f + 3] = v.w;
        }
    }
    {
        const int f = (t & 31) * 4;
        #pragma unroll
        for (int it = 0; it < 8; ++it) {
            const int o = (t >> 5) + it * 8;
            float4 v = *(const float4*)&W[(size_t)(ohalf * 64 + o) * F_ + f];
            Wt[f][o] = v.x; Wt[f + 1][o] = v.y;
            Wt[f + 2][o] = v.z; Wt[f + 3][o] = v.w;
        }
    }
    {
        const int f = t & 127;
        const int which = t >> 7;
        const float* av = a + which * 128;
        float acc = 0.f;
        for (int o = 0; o < 128; ++o)
            acc += W[(size_t)o * F_ + f] * av[o];
        if (which == 0) wsm[f] = acc; else wtm[f] = acc;
    }
    __syncthreads();

    const int o4 = t & 15;
    const int r4 = t >> 4;
    float acc[4][4];
    #pragma unroll
    for (int i = 0; i < 4; ++i)
        #pragma unroll
        for (int j = 0; j < 4; ++j) acc[i][j] = 0.f;

    #pragma unroll 4
    for (int k = 0; k < 128; ++k) {
        float4 w = *(const float4*)&Wt[k][o4 * 4];
        float h0 = h_s[r4 * 4 + 0][k];
        float h1 = h_s[r4 * 4 + 1][k];
        float h2 = h_s[r4 * 4 + 2][k];
        float h3 = h_s[r4 * 4 + 3][k];
        acc[0][0] += h0 * w.x; acc[0][1] += h0 * w.y; acc[0][2] += h0 * w.z; acc[0][3] += h0 * w.w;
        acc[1][0] += h1 * w.x; acc[1][1] += h1 * w.y; acc[1][2] += h1 * w.z; acc[1][3] += h1 * w.w;
        acc[2][0] += h2 * w.x; acc[2][1] += h2 * w.y; acc[2][2] += h2 * w.z; acc[2][3] += h2 * w.w;
        acc[3][0] += h3 * w.x; acc[3][1] += h3 * w.y; acc[3][2] += h3 * w.z; acc[3][3] += h3 * w.w;
    }

    {
        const int Rbase = r0 + r4 * 4;
        const int b    = Rbase >> 11;
        const int jj   = Rbase & 2047;
        const int jblk = jj >> 5;
        const int k8   = (jj >> 3) & 3;
        const int kk   = jj & 7;
        #pragma unroll
        for (int jo = 0; jo < 4; ++jo) {
            const int o = ohalf * 64 + o4 * 4 + jo;
            size_t off = ((size_t)(b * 64 + jblk) * 128 + o) * 32 + k8 * 8 + kk;
            union { _Float16 x[4]; uint2 u; } pk;
            pk.x[0] = (_Float16)acc[0][jo];
            pk.x[1] = (_Float16)acc[1][jo];
            pk.x[2] = (_Float16)acc[2][jo];
            pk.x[3] = (_Float16)acc[3][jo];
            *(uint2*)(WhH + off) = pk.u;
        }
    }

    {
        const int r = t & 63, part = t >> 6;
        float as_ = 0.f, at_ = 0.f;
        const int kb = part * 32;
        for (int k = kb; k < kb + 32; ++k) {
            float hv = h_s[r][k];
            as_ += hv * wsm[k];
            at_ += hv * wtm[k];
        }
        sred[r][part] = as_; tred[r][part] = at_;
    }
    __syncthreads();
    if (ohalf == 0 && t < 64) {
        sv[r0 + t] = sred[t][0] + sred[t][1] + sred[t][2] + sred[t][3];
        tv[r0 + t] = tred[t][0] + tred[t][1] + tred[t][2] + tred[t][3];
    }
}

// ---------------------------------------------------------------------------
// Kernel 2: flash-GAT, LDS-staged double-buffered pipeline, split-j.
// 1024 blocks = 8 batch x 32 i-tiles(64 rows) x 4 j-slices(512 j).
// 4 waves; wave wv owns rows i0+wv*16 (one A-frag), all sweep the SAME
// 16 chunks of 32 j.  WhH chunk (8 KB contiguous) staged into double-buffer
// LDS by all 256 threads (register-prefetch 1 chunk ahead, 2 barriers/chunk);
// adj read per-lane (int4 x2) register-prefetched 1 chunk ahead; t-slice
// prestaged in LDS.  Writes partial O (C-frag layout) + partial l.
// ---------------------------------------------------------------------------
__global__ __launch_bounds__(256, 3) void k_attn(
    const _Float16* __restrict__ WhH, const float* __restrict__ sv,
    const float* __restrict__ tv, const int* __restrict__ adj,
    float* __restrict__ Po, float* __restrict__ Pl)
{
    __shared__ _Float16 whS[2][4096];   // 2 x 8 KB
    __shared__ float tS[512];
    __shared__ float tmr[4];

    const int t   = threadIdx.x;
    const int b   = blockIdx.x & 7;
    const int rem = blockIdx.x >> 3;
    const int i0  = (rem & 31) * 64;
    const int jh  = rem >> 5;            // 0..3
    const int jbase = jh * 512;

    const float* tb = tv + ((size_t)b << 11);

    // per-batch tmax (full batch, L2-hot 8 KB)
    float tm = -INFINITY;
    #pragma unroll
    for (int k = 0; k < 8; ++k) tm = fmaxf(tm, tb[t + k * 256]);
    #pragma unroll
    for (int k = 32; k; k >>= 1) tm = fmaxf(tm, __shfl_xor(tm, k, 64));
    if ((t & 63) == 0) tmr[t >> 6] = tm;

    // stage t-slice
    tS[t]       = tb[jbase + t];
    tS[t + 256] = tb[jbase + t + 256];

    const int wv   = t >> 6;
    const int lane = t & 63;
    const int m_   = lane & 15;
    const int q_   = lane >> 4;

    const int   girow = (b << 11) + i0 + wv * 16 + m_;
    const float s_i   = sv[girow];
    const int*  arow  = adj + ((size_t)girow << 11) + jbase + q_ * 8;

    // WhH chunk base for this (batch, j-slice)
    const _Float16* whc = WhH + (((size_t)b * 64 + jh * 16) << 12);

    // ---- prologue: stage chunk 0 ----
    {
        uint4 w0 = *(const uint4*)(whc + (size_t)t * 8);
        uint4 w1 = *(const uint4*)(whc + (size_t)(t + 256) * 8);
        *(uint4*)&whS[0][t * 8]         = w0;
        *(uint4*)&whS[0][(t + 256) * 8] = w1;
    }
    int4 aC0 = *(const int4*)(arow);
    int4 aC1 = *(const int4*)(arow + 4);
    __syncthreads();
    const float M_i = fmaxf(s_i + fmaxf(fmaxf(tmr[0], tmr[1]), fmaxf(tmr[2], tmr[3])), 0.f);

    f32x4 acc[8];
    #pragma unroll
    for (int n = 0; n < 8; ++n) acc[n] = (f32x4){0.f, 0.f, 0.f, 0.f};
    float lsum = 0.f;

    for (int jj = 0; jj < 16; ++jj) {
        const int cur  = jj & 1;
        const int nxt  = (jj + 1) & 15;          // wrap: harmless re-stage
        const int nbuf = (jj + 1) & 1;

        // issue next-chunk global loads early (regs)
        const _Float16* whn = whc + ((size_t)nxt << 12);
        uint4 w0 = *(const uint4*)(whn + (size_t)t * 8);
        uint4 w1 = *(const uint4*)(whn + (size_t)(t + 256) * 8);
        int4 aN0 = *(const int4*)(arow + nxt * 32);
        int4 aN1 = *(const int4*)(arow + nxt * 32 + 4);

        // P values for current chunk (A-frag layout: row m_, k = q_*8+kk)
        float4 tL = *(const float4*)&tS[jj * 32 + q_ * 8];
        float4 tH = *(const float4*)&tS[jj * 32 + q_ * 8 + 4];
        float tvk[8] = {tL.x, tL.y, tL.z, tL.w, tH.x, tH.y, tH.z, tH.w};
        int   avk[8] = {aC0.x, aC0.y, aC0.z, aC0.w, aC1.x, aC1.y, aC1.z, aC1.w};
        half8 af;
        #pragma unroll
        for (int k = 0; k < 8; ++k) {
            float e = s_i + tvk[k]; e = fmaxf(e, 0.2f * e);
            float p = avk[k] ? __expf(e - M_i) : 0.f;
            lsum += p;
            af[k] = (_Float16)p;
        }

        // MFMAs from staged LDS
        #pragma unroll
        for (int n = 0; n < 8; ++n) {
            half8 bf = *(const half8*)&whS[cur][n * 512 + m_ * 32 + q_ * 8];
            acc[n] = __builtin_amdgcn_mfma_f32_16x16x32_f16(af, bf, acc[n], 0, 0, 0);
        }

        __syncthreads();                          // reads of whS done
        *(uint4*)&whS[nbuf][t * 8]         = w0;
        *(uint4*)&whS[nbuf][(t + 256) * 8] = w1;
        aC0 = aN0; aC1 = aN1;
        __syncthreads();                          // next buffer visible
    }

    // partial l: reduce over q-lanes (k-dim), lanes q==0 hold rows
    lsum += __shfl_xor(lsum, 16, 64);
    lsum += __shfl_xor(lsum, 32, 64);
    if (q_ == 0) Pl[(size_t)jh * (B_ * N_) + girow] = lsum;

    // partial O: C/D layout row=q_*4+r, col=n*16+m_
    float* po = Po + (size_t)jh * ((size_t)B_ * N_ * F_)
              + (((size_t)((b << 11) + i0 + wv * 16)) << 7);
    #pragma unroll
    for (int n = 0; n < 8; ++n)
        #pragma unroll
        for (int r = 0; r < 4; ++r)
            po[(size_t)(q_ * 4 + r) * F_ + n * 16 + m_] = acc[n][r];
}

// ---------------------------------------------------------------------------
// Kernel 3: combine 4 j-slice partials: out = (sum Po) / (sum Pl), 0-guarded.
// 2048 blocks x 256 threads, one float4 per thread.
// ---------------------------------------------------------------------------
__global__ __launch_bounds__(256) void k_comb(
    const float* __restrict__ Po, const float* __restrict__ Pl,
    float* __restrict__ out)
{
    const int idx = blockIdx.x * 256 + threadIdx.x;   // 0..524287
    const int gi  = idx >> 5;
    const int o4  = (idx & 31) * 4;
    const size_t stride = (size_t)B_ * N_ * F_;

    float4 v = *(const float4*)&Po[(size_t)gi * F_ + o4];
    float  l = Pl[gi];
    #pragma unroll
    for (int jh = 1; jh < 4; ++jh) {
        float4 u = *(const float4*)&Po[jh * stride + (size_t)gi * F_ + o4];
        v.x += u.x; v.y += u.y; v.z += u.z; v.w += u.w;
        l += Pl[jh * (B_ * N_) + gi];
    }
    const float sc = l > 0.f ? 1.f / l : 0.f;
    float4 r = {v.x * sc, v.y * sc, v.z * sc, v.w * sc};
    *(float4*)&out[(size_t)gi * F_ + o4] = r;
}

extern "C" void kernel_launch(void* const* d_in, const int* in_sizes, int n_in,
                              void* d_out, int out_size, void* d_ws, size_t ws_size,
                              hipStream_t stream) {
    const float* h   = (const float*)d_in[0];
    const int*   adj = (const int*)d_in[1];
    const float* W   = (const float*)d_in[2];
    const float* a   = (const float*)d_in[3];
    float* out = (float*)d_out;

    char* ws = (char*)d_ws;
    _Float16* WhH = (_Float16*)ws;                        // 4 MB
    float* sv = (float*)(ws + (size_t)4 * 1024 * 1024);   // 64 KB
    float* tv = sv + (size_t)B_ * N_;                     // 64 KB
    float* Po = (float*)(ws + (size_t)8 * 1024 * 1024);   // 32 MB
    float* Pl = (float*)(ws + (size_t)40 * 1024 * 1024);  // 256 KB

    k_gemm<<<512, 256, 0, stream>>>(h, W, a, WhH, sv, tv);
    k_attn<<<1024, 256, 0, stream>>>(WhH, sv, tv, adj, Po, Pl);
    k_comb<<<2048, 256, 0, stream>>>(Po, Pl, out);
}